// Round 2
// baseline (402.867 us; speedup 1.0000x reference)
//
#include <hip/hip_runtime.h>
#include <math.h>

#define BB 64
#define MM 128
#define DDIM 2048
#define KK 32
#define OUTROW (DDIM + KK*DDIM)  // 67584

typedef __attribute__((ext_vector_type(8))) short bf16x8;
typedef __attribute__((ext_vector_type(4))) float f32x4;

// float -> bf16 RNE (inputs finite; no NaN handling needed)
__device__ __forceinline__ short f2bf(float f) {
  unsigned u = __builtin_bit_cast(unsigned, f);
  u += 0x7fffu + ((u >> 16) & 1u);
  return (short)(u >> 16);
}
__device__ __forceinline__ unsigned pack2(float lo, float hi) {
  return (unsigned)(unsigned short)f2bf(lo) | ((unsigned)(unsigned short)f2bf(hi) << 16);
}

// ---------------------------------------------------------------------------
// Single-use 8-block barrier (one int per batch, memset-0 before launch).
// Per-batch, NOT grid-wide: only the 8 blocks of one batch wait on each
// other, so a plain (non-cooperative) launch is safe — any batch whose 8
// blocks are resident progresses and retires, freeing slots; no global
// co-residency requirement, no deadlock. Bounded spin: wrong > hung.
// Agent-scope release (threadfence: wb L2) before arrive; agent-scope
// acquire (inv L1/L2) after — required for cross-XCD visibility.
// ---------------------------------------------------------------------------
__device__ __forceinline__ void batch_barrier(int* bar) {
  __syncthreads();                    // all block stores issued
  __threadfence();                    // release: own stores visible at agent scope
  if (threadIdx.x == 0) {
    __hip_atomic_fetch_add(bar, 1, __ATOMIC_ACQ_REL, __HIP_MEMORY_SCOPE_AGENT);
    int it = 0;
    while (__hip_atomic_load(bar, __ATOMIC_ACQUIRE, __HIP_MEMORY_SCOPE_AGENT) < 8) {
      __builtin_amdgcn_s_sleep(8);
      if (++it > (1 << 20)) break;    // escape hatch
    }
  }
  __syncthreads();
  __threadfence();                    // acquire for all threads of the block
}

// ---------------------------------------------------------------------------
// K0: W fp32 -> bf16 once. 65536 elems, 32 blocks x 256 x 8.
// ---------------------------------------------------------------------------
__global__ __launch_bounds__(256) void k_prep(const float* __restrict__ W,
                                              short* __restrict__ Wb) {
  int i = (blockIdx.x * 256 + threadIdx.x) * 8;
  float4 a = *(const float4*)(W + i);
  float4 b = *(const float4*)(W + i + 4);
  bf16x8 o = {f2bf(a.x), f2bf(a.y), f2bf(a.z), f2bf(a.w),
              f2bf(b.x), f2bf(b.y), f2bf(b.z), f2bf(b.w)};
  *(bf16x8*)(Wb + i) = o;
}

// ---------------------------------------------------------------------------
// K1: fused main kernel. 512 blocks x 256; block bid = (batch b = bid>>3,
// part = bid&7). Phases with per-batch barriers:
//   P1: logits GEMM + softmax for frame-group part (skip fully-invalid)
//   P2: vlad GEMM (d-chunk part) + residual IN REGISTERS + ssq partials
//   P3: norms; scale registers; write vlad part of out ONCE
// Removes k_norm's 33.6MB pass + 2 launch gaps; short batches pipeline
// through phases independently of long ones.
// ---------------------------------------------------------------------------
__global__ __launch_bounds__(256, 2) void k_main(
    const float* __restrict__ x, const int* __restrict__ lengths,
    const short* __restrict__ Wb, const float* __restrict__ Cc,
    float* __restrict__ out, short* __restrict__ aT,
    float* __restrict__ asum_p, float* __restrict__ ssq_part,
    int* bar1, int* bar2) {
  const int t = threadIdx.x, wv = t >> 6, lane = t & 63;
  const int l15 = lane & 15, quad = lane >> 4;
  const int bid = blockIdx.x;
  const int b = bid >> 3, part = bid & 7;
  const int m0 = part * 16;            // frame offset within batch
  const int len = lengths[b];

  __shared__ float sq[4][16];
  __shared__ float lg[4][16][33];
  __shared__ short xbt[4][64][40];     // [wave][d-local][swizzled m], 80B rows
  __shared__ float asl[KK];
  __shared__ float ssw[4][33];
  __shared__ float ssk[KK];

  // ---- P1: logits GEMM (bf16 MFMA) + ssq + softmax + mask ----
  if (m0 < len) {
    const int g0 = bid * 16;           // first frame of group
    const bool av = (m0 + l15) < len;  // lane's frame valid
    const float* xrow = x + (size_t)(g0 + l15) * DDIM + wv * 512 + quad * 8;
    const short* w0   = Wb + l15 * DDIM + wv * 512 + quad * 8;
    const short* w1   = w0 + 16 * DDIM;

    f32x4 c0 = {0.f, 0.f, 0.f, 0.f}, c1 = {0.f, 0.f, 0.f, 0.f};
    float ssq = 0.f;
    #pragma unroll
    for (int h = 0; h < 2; ++h) {
      float4 xa[8], xc[8];
      bf16x8 B0[8], B1[8];
      #pragma unroll
      for (int s = 0; s < 8; ++s) {
        const int so = h * 8 + s;
        if (av) {
          xa[s] = *(const float4*)(xrow + so * 32);
          xc[s] = *(const float4*)(xrow + so * 32 + 4);
        } else {
          xa[s] = make_float4(0.f, 0.f, 0.f, 0.f);
          xc[s] = make_float4(0.f, 0.f, 0.f, 0.f);
        }
        B0[s] = *(const bf16x8*)(w0 + so * 32);
        B1[s] = *(const bf16x8*)(w1 + so * 32);
      }
      #pragma unroll
      for (int s = 0; s < 8; ++s) {
        ssq = fmaf(xa[s].x, xa[s].x, ssq); ssq = fmaf(xa[s].y, xa[s].y, ssq);
        ssq = fmaf(xa[s].z, xa[s].z, ssq); ssq = fmaf(xa[s].w, xa[s].w, ssq);
        ssq = fmaf(xc[s].x, xc[s].x, ssq); ssq = fmaf(xc[s].y, xc[s].y, ssq);
        ssq = fmaf(xc[s].z, xc[s].z, ssq); ssq = fmaf(xc[s].w, xc[s].w, ssq);
        bf16x8 A = {f2bf(xa[s].x), f2bf(xa[s].y), f2bf(xa[s].z), f2bf(xa[s].w),
                    f2bf(xc[s].x), f2bf(xc[s].y), f2bf(xc[s].z), f2bf(xc[s].w)};
        c0 = __builtin_amdgcn_mfma_f32_16x16x32_bf16(A, B0[s], c0, 0, 0, 0);
        c1 = __builtin_amdgcn_mfma_f32_16x16x32_bf16(A, B1[s], c1, 0, 0, 0);
      }
    }

    ssq += __shfl_xor(ssq, 16, 64);
    ssq += __shfl_xor(ssq, 32, 64);
    if (quad == 0) sq[wv][l15] = ssq;
    // C layout: row(frame) = quad*4+reg, col(k) = l15
    #pragma unroll
    for (int r = 0; r < 4; ++r) {
      lg[wv][quad * 4 + r][l15]      = c0[r];
      lg[wv][quad * 4 + r][16 + l15] = c1[r];
    }
    __syncthreads();

    // 16 threads per frame, 2 clusters each
    const int fr = t >> 4, kk = (t & 15) * 2;
    float s0 = 0.f, s1 = 0.f;
    #pragma unroll
    for (int w = 0; w < 4; ++w) { s0 += lg[w][fr][kk]; s1 += lg[w][fr][kk + 1]; }
    float ss  = sq[0][fr] + sq[1][fr] + sq[2][fr] + sq[3][fr];
    float inv = 1.f / fmaxf(sqrtf(ss), 1e-12f);
    s0 *= inv; s1 *= inv;
    float mx = fmaxf(s0, s1);
    mx = fmaxf(mx, __shfl_xor(mx, 1, 64));
    mx = fmaxf(mx, __shfl_xor(mx, 2, 64));
    mx = fmaxf(mx, __shfl_xor(mx, 4, 64));
    mx = fmaxf(mx, __shfl_xor(mx, 8, 64));
    float e0 = __expf(s0 - mx), e1 = __expf(s1 - mx);
    float se = e0 + e1;
    se += __shfl_xor(se, 1, 64);
    se += __shfl_xor(se, 2, 64);
    se += __shfl_xor(se, 4, 64);
    se += __shfl_xor(se, 8, 64);
    const bool valid = (m0 + fr) < len;
    float rr = valid ? (1.f / se) : 0.f;
    float a0 = e0 * rr, a1 = e1 * rr;

    __syncthreads();                   // done reading lg; reuse for asum
    lg[0][fr][kk] = a0; lg[0][fr][kk + 1] = a1;
    __syncthreads();
    if (t < KK) {
      float s = 0.f;
      #pragma unroll
      for (int f = 0; f < 16; ++f) s += lg[0][f][t];
      asum_p[(size_t)bid * KK + t] = s;
    }
    // a' = a * invn, transposed store [b][k][m]
    short* ap = aT + (size_t)b * KK * MM + m0 + fr;
    ap[(size_t)kk * MM]       = f2bf(a0 * inv);
    ap[(size_t)(kk + 1) * MM] = f2bf(a1 * inv);
  } else {
    // fully-invalid frame group: a == 0 -> write zeros directly.
    if (t < KK) asum_p[(size_t)bid * KK + t] = 0.f;
    const int zk = t >> 3, zoff = (t & 7) * 2;   // 32 k x 16 m = 1024B
    *(unsigned*)(aT + (size_t)b * KK * MM + (size_t)zk * MM + m0 + zoff) = 0u;
  }
  batch_barrier(bar1 + b);

  // ---- P2: vlad GEMM + residual (registers) + ssq partials + avgpool ----
  const int dc = part;
  const int dw0 = dc * 256 + wv * 64;  // wave d-base
  f32x4 acc[2][4];
  {
    if (t < KK) {
      float s = 0.f;
      #pragma unroll
      for (int p = 0; p < 8; ++p) s += asum_p[(size_t)(b * 8 + p) * KK + t];
      asl[t] = s;
    }

    const float* xb  = x  + (size_t)b * MM * DDIM;
    const short* at0 = aT + (size_t)b * KK * MM + l15 * MM + quad * 8;

    const int q4   = l15 * 4;          // lane's 4 staged d-rows
    const int mrow = quad * 2;         // even m within pass group
    const int keyw = l15 & 3;          // store swizzle key
    const int keyr = (l15 >> 2) & 3;   // read swizzle key

    // preload A-frags (L2-hot)
    bf16x8 A0[4], A1[4];
    #pragma unroll
    for (int ms = 0; ms < 4; ++ms) {
      A0[ms] = *(const bf16x8*)(at0 + ms * 32);
      A1[ms] = *(const bf16x8*)(at0 + 16 * MM + ms * 32);
    }

    // preload all x (32 independent float4 loads in flight, masked)
    float4 v0[16], v1[16];
    #pragma unroll
    for (int ms = 0; ms < 4; ++ms) {
      #pragma unroll
      for (int p = 0; p < 4; ++p) {
        const int m = ms * 32 + p * 8 + mrow;
        const float* xr = xb + (size_t)m * DDIM + dw0 + q4;
        v0[ms * 4 + p] = (m < len) ? *(const float4*)xr
                                   : make_float4(0.f, 0.f, 0.f, 0.f);
        v1[ms * 4 + p] = (m + 1 < len) ? *(const float4*)(xr + DDIM)
                                       : make_float4(0.f, 0.f, 0.f, 0.f);
      }
    }

    // avgpool (zero-fill makes masking free)
    float avg[4] = {0.f, 0.f, 0.f, 0.f};
    #pragma unroll
    for (int i = 0; i < 16; ++i) {
      avg[0] += v0[i].x + v1[i].x;
      avg[1] += v0[i].y + v1[i].y;
      avg[2] += v0[i].z + v1[i].z;
      avg[3] += v0[i].w + v1[i].w;
    }

    #pragma unroll
    for (int kt = 0; kt < 2; ++kt)
      #pragma unroll
      for (int nt = 0; nt < 4; ++nt) acc[kt][nt] = (f32x4){0.f, 0.f, 0.f, 0.f};

    #pragma unroll
    for (int ms = 0; ms < 4; ++ms) {
      #pragma unroll
      for (int p = 0; p < 4; ++p) {
        const int i = ms * 4 + p;
        const int mls = (p ^ keyw) * 8 + mrow;  // swizzled m-slot
        *(unsigned*)&xbt[wv][q4 + 0][mls] = pack2(v0[i].x, v1[i].x);
        *(unsigned*)&xbt[wv][q4 + 1][mls] = pack2(v0[i].y, v1[i].y);
        *(unsigned*)&xbt[wv][q4 + 2][mls] = pack2(v0[i].z, v1[i].z);
        *(unsigned*)&xbt[wv][q4 + 3][mls] = pack2(v0[i].w, v1[i].w);
      }
      // wave-private tile: same-wave DS ordering is program order
      #pragma unroll
      for (int nt = 0; nt < 4; ++nt) {
        bf16x8 B = *(const bf16x8*)&xbt[wv][nt * 16 + l15][(quad ^ keyr) * 8];
        acc[0][nt] = __builtin_amdgcn_mfma_f32_16x16x32_bf16(A0[ms], B, acc[0][nt], 0, 0, 0);
        acc[1][nt] = __builtin_amdgcn_mfma_f32_16x16x32_bf16(A1[ms], B, acc[1][nt], 0, 0, 0);
      }
    }

    #pragma unroll
    for (int c = 0; c < 4; ++c) {
      avg[c] += __shfl_xor(avg[c], 16, 64);
      avg[c] += __shfl_xor(avg[c], 32, 64);
    }
    if (quad == 0) {
      float rl = 1.f / (float)len;
      *(float4*)(out + (size_t)b * OUTROW + dw0 + q4) =
          make_float4(avg[0] * rl, avg[1] * rl, avg[2] * rl, avg[3] * rl);
    }

    __syncthreads();   // asl ready
    // residual into registers + per-k ssq partials
    #pragma unroll
    for (int kt = 0; kt < 2; ++kt) {
      #pragma unroll
      for (int r = 0; r < 4; ++r) {
        const int k = kt * 16 + quad * 4 + r;
        const float as = asl[k];
        float sqv = 0.f;
        #pragma unroll
        for (int nt = 0; nt < 4; ++nt) {
          const int d = dw0 + nt * 16 + l15;
          float v = acc[kt][nt][r] - as * Cc[(size_t)k * DDIM + d];
          acc[kt][nt][r] = v;
          sqv = fmaf(v, v, sqv);
        }
        sqv += __shfl_xor(sqv, 1, 64);
        sqv += __shfl_xor(sqv, 2, 64);
        sqv += __shfl_xor(sqv, 4, 64);
        sqv += __shfl_xor(sqv, 8, 64);
        if (l15 == 0) ssw[wv][k] = sqv;
      }
    }
    __syncthreads();
    if (t < KK)
      ssq_part[((size_t)dc * BB + b) * KK + t] =
          ssw[0][t] + ssw[1][t] + ssw[2][t] + ssw[3][t];
  }
  batch_barrier(bar2 + b);

  // ---- P3: norms + scale registers + single out write ----
  {
    if (t < KK) {
      float s = 0.f;
      #pragma unroll
      for (int d8 = 0; d8 < 8; ++d8)
        s += ssq_part[((size_t)d8 * BB + b) * KK + t];
      ssk[t] = s;
    }
    __syncthreads();
    float gss = 0.f;
    #pragma unroll
    for (int kk2 = 0; kk2 < KK; ++kk2) {
      float nk = sqrtf(ssk[kk2]);
      float iv = 1.f / fmaxf(nk, 1e-12f);
      float nn = nk * iv;
      gss += nn * nn;
    }
    const float rg = 1.f / fmaxf(sqrtf(gss), 1e-12f);
    float* orow = out + (size_t)b * OUTROW + DDIM;
    #pragma unroll
    for (int kt = 0; kt < 2; ++kt) {
      #pragma unroll
      for (int r = 0; r < 4; ++r) {
        const int k = kt * 16 + quad * 4 + r;
        const float iv = 1.f / fmaxf(sqrtf(ssk[k]), 1e-12f);
        const float sc = iv * rg;
        #pragma unroll
        for (int nt = 0; nt < 4; ++nt)
          orow[(size_t)k * DDIM + dw0 + nt * 16 + l15] = acc[kt][nt][r] * sc;
      }
    }
  }
}

// ---------------------------------------------------------------------------
extern "C" void kernel_launch(void* const* d_in, const int* in_sizes, int n_in,
                              void* d_out, int out_size, void* d_ws, size_t ws_size,
                              hipStream_t stream) {
  const float* x       = (const float*)d_in[0];
  const int*   lengths = (const int*)d_in[1];
  const float* W       = (const float*)d_in[2];
  const float* C       = (const float*)d_in[3];
  float* out = (float*)d_out;

  short* Wb     = (short*)d_ws;                          // 32*2048 shorts
  short* aT     = Wb + (size_t)KK * DDIM;                // 64*32*128 shorts
  float* asum_p = (float*)(aT + (size_t)BB * KK * MM);   // 512*32 floats
  float* ssqp   = asum_p + (size_t)512 * KK;             // 8*64*32 floats
  int*   bars   = (int*)(ssqp + (size_t)8 * BB * KK);    // 2*64 ints

  hipMemsetAsync(bars, 0, 2 * BB * sizeof(int), stream);
  k_prep<<<dim3(32),  256, 0, stream>>>(W, Wb);
  k_main<<<dim3(512), 256, 0, stream>>>(x, lengths, Wb, C, out, aT,
                                        asum_p, ssqp, bars, bars + BB);
}

// Round 4
// 183.846 us; speedup vs baseline: 2.1913x; 2.1913x over previous
//
#include <hip/hip_runtime.h>
#include <math.h>

#define BB 64
#define MM 128
#define DDIM 2048
#define KK 32
#define OUTROW (DDIM + KK*DDIM)  // 67584

typedef __attribute__((ext_vector_type(8))) short bf16x8;
typedef __attribute__((ext_vector_type(4))) float f32x4;

// float -> bf16 RNE (inputs finite; no NaN handling needed)
__device__ __forceinline__ short f2bf(float f) {
  unsigned u = __builtin_bit_cast(unsigned, f);
  u += 0x7fffu + ((u >> 16) & 1u);
  return (short)(u >> 16);
}
__device__ __forceinline__ unsigned pack2(float lo, float hi) {
  return (unsigned)(unsigned short)f2bf(lo) | ((unsigned)(unsigned short)f2bf(hi) << 16);
}

// ---------------------------------------------------------------------------
// K0: W fp32 -> bf16 once. 65536 elems, 32 blocks x 256 x 8.
// ---------------------------------------------------------------------------
__global__ __launch_bounds__(256) void k_prep(const float* __restrict__ W,
                                              short* __restrict__ Wb) {
  int i = (blockIdx.x * 256 + threadIdx.x) * 8;
  float4 a = *(const float4*)(W + i);
  float4 b = *(const float4*)(W + i + 4);
  bf16x8 o = {f2bf(a.x), f2bf(a.y), f2bf(a.z), f2bf(a.w),
              f2bf(b.x), f2bf(b.y), f2bf(b.z), f2bf(b.w)};
  *(bf16x8*)(Wb + i) = o;
}

// ---------------------------------------------------------------------------
// K1: fused logits GEMM (bf16 MFMA) + ssq + softmax + mask.
// Fully-invalid frame groups (m0 >= len, ~37% of blocks for U[1,128]
// lengths) skip the W-stream + 32 MFMAs + softmax entirely and just zero
// their aT/asum slice (verified bit-identical: masked a was 0 anyway).
// Grid 512 x 256; block = 16 frames; 4 waves split D=2048.
// ---------------------------------------------------------------------------
__global__ __launch_bounds__(256, 2) void k_logits(const float* __restrict__ x,
    const int* __restrict__ lengths, const short* __restrict__ Wb,
    short* __restrict__ aT, float* __restrict__ asum_p) {
  const int t = threadIdx.x, wv = t >> 6, lane = t & 63;
  const int l15 = lane & 15, quad = lane >> 4;
  const int fg = blockIdx.x;           // 0..511
  const int g0 = fg * 16;              // first frame of block
  const int b  = fg >> 3;              // 8 blocks per batch
  const int m0 = (fg & 7) * 16;        // frame offset within batch
  const int len = lengths[b];

  if (m0 >= len) {
    // fully-invalid frame group: a == 0 -> write zeros directly, exit.
    if (t < KK) asum_p[(size_t)fg * KK + t] = 0.f;
    const int zk = t >> 3, zoff = (t & 7) * 2;   // 32 k x 16 m = 1024B
    *(unsigned*)(aT + (size_t)b * KK * MM + (size_t)zk * MM + m0 + zoff) = 0u;
    return;
  }

  const bool av = (m0 + l15) < len;    // lane's frame valid (const over loop)
  const float* xrow = x + (size_t)(g0 + l15) * DDIM + wv * 512 + quad * 8;
  const short* w0   = Wb + l15 * DDIM + wv * 512 + quad * 8;
  const short* w1   = w0 + 16 * DDIM;

  f32x4 c0 = {0.f, 0.f, 0.f, 0.f}, c1 = {0.f, 0.f, 0.f, 0.f};
  float ssq = 0.f;
  #pragma unroll
  for (int h = 0; h < 2; ++h) {
    float4 xa[8], xc[8];
    bf16x8 B0[8], B1[8];
    #pragma unroll
    for (int s = 0; s < 8; ++s) {
      const int so = h * 8 + s;
      if (av) {
        xa[s] = *(const float4*)(xrow + so * 32);
        xc[s] = *(const float4*)(xrow + so * 32 + 4);
      } else {
        xa[s] = make_float4(0.f, 0.f, 0.f, 0.f);
        xc[s] = make_float4(0.f, 0.f, 0.f, 0.f);
      }
      B0[s] = *(const bf16x8*)(w0 + so * 32);
      B1[s] = *(const bf16x8*)(w1 + so * 32);
    }
    #pragma unroll
    for (int s = 0; s < 8; ++s) {
      ssq = fmaf(xa[s].x, xa[s].x, ssq); ssq = fmaf(xa[s].y, xa[s].y, ssq);
      ssq = fmaf(xa[s].z, xa[s].z, ssq); ssq = fmaf(xa[s].w, xa[s].w, ssq);
      ssq = fmaf(xc[s].x, xc[s].x, ssq); ssq = fmaf(xc[s].y, xc[s].y, ssq);
      ssq = fmaf(xc[s].z, xc[s].z, ssq); ssq = fmaf(xc[s].w, xc[s].w, ssq);
      bf16x8 A = {f2bf(xa[s].x), f2bf(xa[s].y), f2bf(xa[s].z), f2bf(xa[s].w),
                  f2bf(xc[s].x), f2bf(xc[s].y), f2bf(xc[s].z), f2bf(xc[s].w)};
      c0 = __builtin_amdgcn_mfma_f32_16x16x32_bf16(A, B0[s], c0, 0, 0, 0);
      c1 = __builtin_amdgcn_mfma_f32_16x16x32_bf16(A, B1[s], c1, 0, 0, 0);
    }
  }

  ssq += __shfl_xor(ssq, 16, 64);
  ssq += __shfl_xor(ssq, 32, 64);
  __shared__ float sq[4][16];
  __shared__ float lg[4][16][33];
  if (quad == 0) sq[wv][l15] = ssq;
  // C layout: row(frame) = quad*4+reg, col(k) = l15
  #pragma unroll
  for (int r = 0; r < 4; ++r) {
    lg[wv][quad * 4 + r][l15]      = c0[r];
    lg[wv][quad * 4 + r][16 + l15] = c1[r];
  }
  __syncthreads();

  // 16 threads per frame, 2 clusters each
  const int fr = t >> 4, kk = (t & 15) * 2;
  float s0 = 0.f, s1 = 0.f;
  #pragma unroll
  for (int w = 0; w < 4; ++w) { s0 += lg[w][fr][kk]; s1 += lg[w][fr][kk + 1]; }
  float ss  = sq[0][fr] + sq[1][fr] + sq[2][fr] + sq[3][fr];
  float inv = 1.f / fmaxf(sqrtf(ss), 1e-12f);
  s0 *= inv; s1 *= inv;
  float mx = fmaxf(s0, s1);
  mx = fmaxf(mx, __shfl_xor(mx, 1, 64));
  mx = fmaxf(mx, __shfl_xor(mx, 2, 64));
  mx = fmaxf(mx, __shfl_xor(mx, 4, 64));
  mx = fmaxf(mx, __shfl_xor(mx, 8, 64));
  float e0 = __expf(s0 - mx), e1 = __expf(s1 - mx);
  float se = e0 + e1;
  se += __shfl_xor(se, 1, 64);
  se += __shfl_xor(se, 2, 64);
  se += __shfl_xor(se, 4, 64);
  se += __shfl_xor(se, 8, 64);
  const bool valid = (m0 + fr) < len;
  float rr = valid ? (1.f / se) : 0.f;
  float a0 = e0 * rr, a1 = e1 * rr;

  __syncthreads();                    // done reading lg; reuse for asum
  lg[0][fr][kk] = a0; lg[0][fr][kk + 1] = a1;
  __syncthreads();
  if (t < KK) {
    float s = 0.f;
    #pragma unroll
    for (int f = 0; f < 16; ++f) s += lg[0][f][t];
    asum_p[(size_t)fg * KK + t] = s;
  }
  // a' = a * invn, transposed store [b][k][m]
  short* ap = aT + (size_t)b * KK * MM + m0 + fr;
  ap[(size_t)kk * MM]       = f2bf(a0 * inv);
  ap[(size_t)(kk + 1) * MM] = f2bf(a1 * inv);
}

// ---------------------------------------------------------------------------
// K2: vlad GEMM (bf16 MFMA) + residual + ssq partials + avgpool, then
// "last-arriver finishes": after writing its unscaled residuals + ssq
// partials, each block does ONE release fence + ONE ACQ_REL atomicAdd on a
// per-batch counter (NO polling — round 2 showed acquire-spin thrashes the
// per-XCD L2s). The 8th arriver acquires and applies intra+global norms to
// the whole batch row, replacing the k_norm kernel (launch + 33MB pass).
// Grid (8 dc, 64 b) x 256.
// ---------------------------------------------------------------------------
__global__ __launch_bounds__(256, 2) void k_vlad(const float* __restrict__ x,
    const int* __restrict__ lengths, const float* __restrict__ Cc,
    const short* __restrict__ aT, const float* __restrict__ asum_p,
    float* __restrict__ out, float* __restrict__ ssq_part, int* cnt) {
  const int t = threadIdx.x, wv = t >> 6, lane = t & 63;
  const int l15 = lane & 15, quad = lane >> 4;
  const int dc = blockIdx.x, b = blockIdx.y;
  const int dw0 = dc * 256 + wv * 64;   // wave d-base
  const int len = lengths[b];

  __shared__ short xbt[4][64][40];      // [wave][d-local][swizzled m], 80B rows
  __shared__ float asl[KK];
  __shared__ float ssw[4][33];
  __shared__ float ssk[KK];
  __shared__ float scl[KK];
  __shared__ int lastf;

  if (t < KK) {
    float s = 0.f;
    #pragma unroll
    for (int p = 0; p < 8; ++p) s += asum_p[(size_t)(b * 8 + p) * KK + t];
    asl[t] = s;
  }

  const float* xb  = x  + (size_t)b * MM * DDIM;
  const short* at0 = aT + (size_t)b * KK * MM + l15 * MM + quad * 8;

  const int q4   = l15 * 4;             // lane's 4 staged d-rows
  const int mrow = quad * 2;            // even m within pass group
  const int keyw = l15 & 3;             // store swizzle key
  const int keyr = (l15 >> 2) & 3;      // read swizzle key

  // ---- preload A-frags (L2-hot, 32B/lane x 4) ----
  bf16x8 A0[4], A1[4];
  #pragma unroll
  for (int ms = 0; ms < 4; ++ms) {
    A0[ms] = *(const bf16x8*)(at0 + ms * 32);
    A1[ms] = *(const bf16x8*)(at0 + 16 * MM + ms * 32);
  }

  // ---- preload all x (32 independent float4 loads in flight, masked) ----
  float4 v0[16], v1[16];
  #pragma unroll
  for (int ms = 0; ms < 4; ++ms) {
    #pragma unroll
    for (int p = 0; p < 4; ++p) {
      const int m = ms * 32 + p * 8 + mrow;
      const float* xr = xb + (size_t)m * DDIM + dw0 + q4;
      v0[ms * 4 + p] = (m < len) ? *(const float4*)xr
                                 : make_float4(0.f, 0.f, 0.f, 0.f);
      v1[ms * 4 + p] = (m + 1 < len) ? *(const float4*)(xr + DDIM)
                                     : make_float4(0.f, 0.f, 0.f, 0.f);
    }
  }

  // avgpool (zero-fill makes masking free)
  float avg[4] = {0.f, 0.f, 0.f, 0.f};
  #pragma unroll
  for (int i = 0; i < 16; ++i) {
    avg[0] += v0[i].x + v1[i].x;
    avg[1] += v0[i].y + v1[i].y;
    avg[2] += v0[i].z + v1[i].z;
    avg[3] += v0[i].w + v1[i].w;
  }

  f32x4 acc[2][4];
  #pragma unroll
  for (int kt = 0; kt < 2; ++kt)
    #pragma unroll
    for (int nt = 0; nt < 4; ++nt) acc[kt][nt] = (f32x4){0.f, 0.f, 0.f, 0.f};

  #pragma unroll
  for (int ms = 0; ms < 4; ++ms) {
    #pragma unroll
    for (int p = 0; p < 4; ++p) {
      const int i = ms * 4 + p;
      const int mls = (p ^ keyw) * 8 + mrow;  // swizzled m-slot
      *(unsigned*)&xbt[wv][q4 + 0][mls] = pack2(v0[i].x, v1[i].x);
      *(unsigned*)&xbt[wv][q4 + 1][mls] = pack2(v0[i].y, v1[i].y);
      *(unsigned*)&xbt[wv][q4 + 2][mls] = pack2(v0[i].z, v1[i].z);
      *(unsigned*)&xbt[wv][q4 + 3][mls] = pack2(v0[i].w, v1[i].w);
    }
    // wave-private tile: same-wave DS ordering is program order
    #pragma unroll
    for (int nt = 0; nt < 4; ++nt) {
      bf16x8 B = *(const bf16x8*)&xbt[wv][nt * 16 + l15][(quad ^ keyr) * 8];
      acc[0][nt] = __builtin_amdgcn_mfma_f32_16x16x32_bf16(A0[ms], B, acc[0][nt], 0, 0, 0);
      acc[1][nt] = __builtin_amdgcn_mfma_f32_16x16x32_bf16(A1[ms], B, acc[1][nt], 0, 0, 0);
    }
  }

  #pragma unroll
  for (int c = 0; c < 4; ++c) {
    avg[c] += __shfl_xor(avg[c], 16, 64);
    avg[c] += __shfl_xor(avg[c], 32, 64);
  }
  if (quad == 0) {
    float rl = 1.f / (float)len;
    *(float4*)(out + (size_t)b * OUTROW + dw0 + q4) =
        make_float4(avg[0] * rl, avg[1] * rl, avg[2] * rl, avg[3] * rl);
  }

  __syncthreads();   // asl ready
  float* orow = out + (size_t)b * OUTROW + DDIM;
  #pragma unroll
  for (int kt = 0; kt < 2; ++kt) {
    #pragma unroll
    for (int r = 0; r < 4; ++r) {
      const int k = kt * 16 + quad * 4 + r;
      const float as = asl[k];
      float sqv = 0.f;
      #pragma unroll
      for (int nt = 0; nt < 4; ++nt) {
        const int d = dw0 + nt * 16 + l15;
        float v = acc[kt][nt][r] - as * Cc[(size_t)k * DDIM + d];
        orow[(size_t)k * DDIM + d] = v;
        sqv = fmaf(v, v, sqv);
      }
      sqv += __shfl_xor(sqv, 1, 64);
      sqv += __shfl_xor(sqv, 2, 64);
      sqv += __shfl_xor(sqv, 4, 64);
      sqv += __shfl_xor(sqv, 8, 64);
      if (l15 == 0) ssw[wv][k] = sqv;
    }
  }
  __syncthreads();
  if (t < KK)
    ssq_part[((size_t)dc * BB + b) * KK + t] =
        ssw[0][t] + ssw[1][t] + ssw[2][t] + ssw[3][t];

  // ---- last-arriver finishes the batch (no polling) ----
  __syncthreads();                      // all stores of this block retired (vmcnt)
  if (t == 0) {
    __threadfence();                    // release: wb dirty L2 -> visible at agent scope
    int old = __hip_atomic_fetch_add(cnt + b, 1, __ATOMIC_ACQ_REL,
                                     __HIP_MEMORY_SCOPE_AGENT);
    lastf = (old == 7);
    if (old == 7) __threadfence();      // acquire: inv stale L1/L2 before re-reads
  }
  __syncthreads();
  if (!lastf) return;

  // P3 (one block per batch): intra + global norms, scale batch vlad row.
  if (t < KK) {
    float s = 0.f;
    #pragma unroll
    for (int d8 = 0; d8 < 8; ++d8)
      s += ssq_part[((size_t)d8 * BB + b) * KK + t];
    ssk[t] = s;
  }
  __syncthreads();
  float gss = 0.f;
  #pragma unroll
  for (int kk2 = 0; kk2 < KK; ++kk2) {
    float nk = sqrtf(ssk[kk2]);
    float iv = 1.f / fmaxf(nk, 1e-12f);
    float nn = nk * iv;
    gss += nn * nn;
  }
  const float rg = 1.f / fmaxf(sqrtf(gss), 1e-12f);
  if (t < KK) scl[t] = rg / fmaxf(sqrtf(ssk[t]), 1e-12f);
  __syncthreads();
  #pragma unroll
  for (int kk2 = 0; kk2 < KK; ++kk2) {
    const float sc = scl[kk2];
    float4* row = (float4*)(orow + (size_t)kk2 * DDIM);
    float4 u0 = row[t], u1 = row[t + 256];
    u0.x *= sc; u0.y *= sc; u0.z *= sc; u0.w *= sc;
    u1.x *= sc; u1.y *= sc; u1.z *= sc; u1.w *= sc;
    row[t] = u0; row[t + 256] = u1;
  }
}

// ---------------------------------------------------------------------------
extern "C" void kernel_launch(void* const* d_in, const int* in_sizes, int n_in,
                              void* d_out, int out_size, void* d_ws, size_t ws_size,
                              hipStream_t stream) {
  const float* x       = (const float*)d_in[0];
  const int*   lengths = (const int*)d_in[1];
  const float* W       = (const float*)d_in[2];
  const float* C       = (const float*)d_in[3];
  float* out = (float*)d_out;

  short* Wb     = (short*)d_ws;                          // 32*2048 shorts
  short* aT     = Wb + (size_t)KK * DDIM;                // 64*32*128 shorts
  float* asum_p = (float*)(aT + (size_t)BB * KK * MM);   // 512*32 floats
  float* ssqp   = asum_p + (size_t)512 * KK;             // 8*64*32 floats
  int*   cnt    = (int*)(ssqp + (size_t)8 * BB * KK);    // 64 ints

  hipMemsetAsync(cnt, 0, BB * sizeof(int), stream);
  k_prep  <<<dim3(32),    256, 0, stream>>>(W, Wb);
  k_logits<<<dim3(512),   256, 0, stream>>>(x, lengths, Wb, aT, asum_p);
  k_vlad  <<<dim3(8, BB), 256, 0, stream>>>(x, lengths, C, aT, asum_p,
                                            out, ssqp, cnt);
}

// Round 5
// 145.670 us; speedup vs baseline: 2.7656x; 1.2621x over previous
//
#include <hip/hip_runtime.h>
#include <math.h>

#define BB 64
#define MM 128
#define DDIM 2048
#define KK 32
#define OUTROW (DDIM + KK*DDIM)  // 67584

typedef __attribute__((ext_vector_type(8))) short bf16x8;
typedef __attribute__((ext_vector_type(4))) float f32x4;

// float -> bf16 RNE (inputs finite; no NaN handling needed)
__device__ __forceinline__ short f2bf(float f) {
  unsigned u = __builtin_bit_cast(unsigned, f);
  u += 0x7fffu + ((u >> 16) & 1u);
  return (short)(u >> 16);
}
__device__ __forceinline__ unsigned pack2(float lo, float hi) {
  return (unsigned)(unsigned short)f2bf(lo) | ((unsigned)(unsigned short)f2bf(hi) << 16);
}

// ---------------------------------------------------------------------------
// K0: W fp32 -> bf16 once. 65536 elems, 32 blocks x 256 x 8.
// ---------------------------------------------------------------------------
__global__ __launch_bounds__(256) void k_prep(const float* __restrict__ W,
                                              short* __restrict__ Wb) {
  int i = (blockIdx.x * 256 + threadIdx.x) * 8;
  float4 a = *(const float4*)(W + i);
  float4 b = *(const float4*)(W + i + 4);
  bf16x8 o = {f2bf(a.x), f2bf(a.y), f2bf(a.z), f2bf(a.w),
              f2bf(b.x), f2bf(b.y), f2bf(b.z), f2bf(b.w)};
  *(bf16x8*)(Wb + i) = o;
}

// ---------------------------------------------------------------------------
// K1: fused logits GEMM (bf16 MFMA) + ssq + softmax + mask.
// Fully-invalid frame groups (m0 >= len) skip the W-stream + 32 MFMAs +
// softmax and just zero their aT/asum slice (correctness proven in r4;
// small contention win only — grid is co-resident so not critical-path).
// Grid 512 x 256; block = 16 frames; 4 waves split D=2048.
// ---------------------------------------------------------------------------
__global__ __launch_bounds__(256, 2) void k_logits(const float* __restrict__ x,
    const int* __restrict__ lengths, const short* __restrict__ Wb,
    short* __restrict__ aT, float* __restrict__ asum_p) {
  const int t = threadIdx.x, wv = t >> 6, lane = t & 63;
  const int l15 = lane & 15, quad = lane >> 4;
  const int fg = blockIdx.x;           // 0..511
  const int g0 = fg * 16;              // first frame of block
  const int b  = fg >> 3;              // 8 blocks per batch
  const int m0 = (fg & 7) * 16;        // frame offset within batch
  const int len = lengths[b];

  if (m0 >= len) {
    // fully-invalid frame group: a == 0 -> write zeros directly, exit.
    if (t < KK) asum_p[(size_t)fg * KK + t] = 0.f;
    const int zk = t >> 3, zoff = (t & 7) * 2;   // 32 k x 16 m = 1024B
    *(unsigned*)(aT + (size_t)b * KK * MM + (size_t)zk * MM + m0 + zoff) = 0u;
    return;
  }

  const bool av = (m0 + l15) < len;    // lane's frame valid (const over loop)
  const float* xrow = x + (size_t)(g0 + l15) * DDIM + wv * 512 + quad * 8;
  const short* w0   = Wb + l15 * DDIM + wv * 512 + quad * 8;
  const short* w1   = w0 + 16 * DDIM;

  f32x4 c0 = {0.f, 0.f, 0.f, 0.f}, c1 = {0.f, 0.f, 0.f, 0.f};
  float ssq = 0.f;
  #pragma unroll
  for (int h = 0; h < 2; ++h) {
    float4 xa[8], xc[8];
    bf16x8 B0[8], B1[8];
    #pragma unroll
    for (int s = 0; s < 8; ++s) {
      const int so = h * 8 + s;
      if (av) {
        xa[s] = *(const float4*)(xrow + so * 32);
        xc[s] = *(const float4*)(xrow + so * 32 + 4);
      } else {
        xa[s] = make_float4(0.f, 0.f, 0.f, 0.f);
        xc[s] = make_float4(0.f, 0.f, 0.f, 0.f);
      }
      B0[s] = *(const bf16x8*)(w0 + so * 32);
      B1[s] = *(const bf16x8*)(w1 + so * 32);
    }
    #pragma unroll
    for (int s = 0; s < 8; ++s) {
      ssq = fmaf(xa[s].x, xa[s].x, ssq); ssq = fmaf(xa[s].y, xa[s].y, ssq);
      ssq = fmaf(xa[s].z, xa[s].z, ssq); ssq = fmaf(xa[s].w, xa[s].w, ssq);
      ssq = fmaf(xc[s].x, xc[s].x, ssq); ssq = fmaf(xc[s].y, xc[s].y, ssq);
      ssq = fmaf(xc[s].z, xc[s].z, ssq); ssq = fmaf(xc[s].w, xc[s].w, ssq);
      bf16x8 A = {f2bf(xa[s].x), f2bf(xa[s].y), f2bf(xa[s].z), f2bf(xa[s].w),
                  f2bf(xc[s].x), f2bf(xc[s].y), f2bf(xc[s].z), f2bf(xc[s].w)};
      c0 = __builtin_amdgcn_mfma_f32_16x16x32_bf16(A, B0[s], c0, 0, 0, 0);
      c1 = __builtin_amdgcn_mfma_f32_16x16x32_bf16(A, B1[s], c1, 0, 0, 0);
    }
  }

  ssq += __shfl_xor(ssq, 16, 64);
  ssq += __shfl_xor(ssq, 32, 64);
  __shared__ float sq[4][16];
  __shared__ float lg[4][16][33];
  if (quad == 0) sq[wv][l15] = ssq;
  // C layout: row(frame) = quad*4+reg, col(k) = l15
  #pragma unroll
  for (int r = 0; r < 4; ++r) {
    lg[wv][quad * 4 + r][l15]      = c0[r];
    lg[wv][quad * 4 + r][16 + l15] = c1[r];
  }
  __syncthreads();

  // 16 threads per frame, 2 clusters each
  const int fr = t >> 4, kk = (t & 15) * 2;
  float s0 = 0.f, s1 = 0.f;
  #pragma unroll
  for (int w = 0; w < 4; ++w) { s0 += lg[w][fr][kk]; s1 += lg[w][fr][kk + 1]; }
  float ss  = sq[0][fr] + sq[1][fr] + sq[2][fr] + sq[3][fr];
  float inv = 1.f / fmaxf(sqrtf(ss), 1e-12f);
  s0 *= inv; s1 *= inv;
  float mx = fmaxf(s0, s1);
  mx = fmaxf(mx, __shfl_xor(mx, 1, 64));
  mx = fmaxf(mx, __shfl_xor(mx, 2, 64));
  mx = fmaxf(mx, __shfl_xor(mx, 4, 64));
  mx = fmaxf(mx, __shfl_xor(mx, 8, 64));
  float e0 = __expf(s0 - mx), e1 = __expf(s1 - mx);
  float se = e0 + e1;
  se += __shfl_xor(se, 1, 64);
  se += __shfl_xor(se, 2, 64);
  se += __shfl_xor(se, 4, 64);
  se += __shfl_xor(se, 8, 64);
  const bool valid = (m0 + fr) < len;
  float rr = valid ? (1.f / se) : 0.f;
  float a0 = e0 * rr, a1 = e1 * rr;

  __syncthreads();                    // done reading lg; reuse for asum
  lg[0][fr][kk] = a0; lg[0][fr][kk + 1] = a1;
  __syncthreads();
  if (t < KK) {
    float s = 0.f;
    #pragma unroll
    for (int f = 0; f < 16; ++f) s += lg[0][f][t];
    asum_p[(size_t)fg * KK + t] = s;
  }
  // a' = a * invn, transposed store [b][k][m]
  short* ap = aT + (size_t)b * KK * MM + m0 + fr;
  ap[(size_t)kk * MM]       = f2bf(a0 * inv);
  ap[(size_t)(kk + 1) * MM] = f2bf(a1 * inv);
}

// ---------------------------------------------------------------------------
// K2: vlad GEMM (bf16 MFMA). Reverted to the verified 4-kernel structure
// (r4 showed per-block agent-scope fences cost ~40us: each release fence
// must write back the XCD's dirty L2 — cross-block handoff belongs at the
// kernel boundary, which flushes ONCE grid-wide).
// NEW vs r0: LDS transpose tile is double-buffered over ms (xbt[ms&1]) —
// the single-buffer version forced stores(ms+1) to wait on reads(ms)
// (same LDS addresses), a 16-deep serial LDS round-trip chain. With two
// buffers the next tile's stores (data already in regs) issue under the
// current MFMAs. Grid (8 dc, 64 b) x 256.
// ---------------------------------------------------------------------------
__global__ __launch_bounds__(256, 2) void k_vlad(const float* __restrict__ x,
    const int* __restrict__ lengths, const float* __restrict__ Cc,
    const short* __restrict__ aT, const float* __restrict__ asum_p,
    float* __restrict__ out, float* __restrict__ ssq_part) {
  const int t = threadIdx.x, wv = t >> 6, lane = t & 63;
  const int l15 = lane & 15, quad = lane >> 4;
  const int dc = blockIdx.x, b = blockIdx.y;
  const int dw0 = dc * 256 + wv * 64;   // wave d-base
  const int len = lengths[b];

  __shared__ short xbt[2][4][64][40];   // [dbuf][wave][d-local][swizzled m]
  __shared__ float asl[KK];
  __shared__ float ssw[4][33];

  if (t < KK) {
    float s = 0.f;
    #pragma unroll
    for (int p = 0; p < 8; ++p) s += asum_p[(size_t)(b * 8 + p) * KK + t];
    asl[t] = s;
  }

  const float* xb  = x  + (size_t)b * MM * DDIM;
  const short* at0 = aT + (size_t)b * KK * MM + l15 * MM + quad * 8;

  const int q4   = l15 * 4;             // lane's 4 staged d-rows
  const int mrow = quad * 2;            // even m within pass group
  const int keyw = l15 & 3;             // store swizzle key
  const int keyr = (l15 >> 2) & 3;      // read swizzle key

  // ---- preload A-frags (L2-hot, 32B/lane x 4) ----
  bf16x8 A0[4], A1[4];
  #pragma unroll
  for (int ms = 0; ms < 4; ++ms) {
    A0[ms] = *(const bf16x8*)(at0 + ms * 32);
    A1[ms] = *(const bf16x8*)(at0 + 16 * MM + ms * 32);
  }

  // ---- preload all x (32 independent float4 loads in flight, masked) ----
  float4 v0[16], v1[16];
  #pragma unroll
  for (int ms = 0; ms < 4; ++ms) {
    #pragma unroll
    for (int p = 0; p < 4; ++p) {
      const int m = ms * 32 + p * 8 + mrow;
      const float* xr = xb + (size_t)m * DDIM + dw0 + q4;
      v0[ms * 4 + p] = (m < len) ? *(const float4*)xr
                                 : make_float4(0.f, 0.f, 0.f, 0.f);
      v1[ms * 4 + p] = (m + 1 < len) ? *(const float4*)(xr + DDIM)
                                     : make_float4(0.f, 0.f, 0.f, 0.f);
    }
  }

  // avgpool (zero-fill makes masking free)
  float avg[4] = {0.f, 0.f, 0.f, 0.f};
  #pragma unroll
  for (int i = 0; i < 16; ++i) {
    avg[0] += v0[i].x + v1[i].x;
    avg[1] += v0[i].y + v1[i].y;
    avg[2] += v0[i].z + v1[i].z;
    avg[3] += v0[i].w + v1[i].w;
  }

  f32x4 acc[2][4];
  #pragma unroll
  for (int kt = 0; kt < 2; ++kt)
    #pragma unroll
    for (int nt = 0; nt < 4; ++nt) acc[kt][nt] = (f32x4){0.f, 0.f, 0.f, 0.f};

  #pragma unroll
  for (int ms = 0; ms < 4; ++ms) {
    const int db = ms & 1;
    #pragma unroll
    for (int p = 0; p < 4; ++p) {
      const int i = ms * 4 + p;
      const int mls = (p ^ keyw) * 8 + mrow;  // swizzled m-slot
      *(unsigned*)&xbt[db][wv][q4 + 0][mls] = pack2(v0[i].x, v1[i].x);
      *(unsigned*)&xbt[db][wv][q4 + 1][mls] = pack2(v0[i].y, v1[i].y);
      *(unsigned*)&xbt[db][wv][q4 + 2][mls] = pack2(v0[i].z, v1[i].z);
      *(unsigned*)&xbt[db][wv][q4 + 3][mls] = pack2(v0[i].w, v1[i].w);
    }
    // wave-private tile: same-wave DS ordering is program order
    #pragma unroll
    for (int nt = 0; nt < 4; ++nt) {
      bf16x8 B = *(const bf16x8*)&xbt[db][wv][nt * 16 + l15][(quad ^ keyr) * 8];
      acc[0][nt] = __builtin_amdgcn_mfma_f32_16x16x32_bf16(A0[ms], B, acc[0][nt], 0, 0, 0);
      acc[1][nt] = __builtin_amdgcn_mfma_f32_16x16x32_bf16(A1[ms], B, acc[1][nt], 0, 0, 0);
    }
  }

  #pragma unroll
  for (int c = 0; c < 4; ++c) {
    avg[c] += __shfl_xor(avg[c], 16, 64);
    avg[c] += __shfl_xor(avg[c], 32, 64);
  }
  if (quad == 0) {
    float rl = 1.f / (float)len;
    *(float4*)(out + (size_t)b * OUTROW + dw0 + q4) =
        make_float4(avg[0] * rl, avg[1] * rl, avg[2] * rl, avg[3] * rl);
  }

  __syncthreads();   // asl ready
  float* orow = out + (size_t)b * OUTROW + DDIM;
  #pragma unroll
  for (int kt = 0; kt < 2; ++kt) {
    #pragma unroll
    for (int r = 0; r < 4; ++r) {
      const int k = kt * 16 + quad * 4 + r;
      const float as = asl[k];
      float sqv = 0.f;
      #pragma unroll
      for (int nt = 0; nt < 4; ++nt) {
        const int d = dw0 + nt * 16 + l15;
        float v = acc[kt][nt][r] - as * Cc[(size_t)k * DDIM + d];
        orow[(size_t)k * DDIM + d] = v;
        sqv = fmaf(v, v, sqv);
      }
      sqv += __shfl_xor(sqv, 1, 64);
      sqv += __shfl_xor(sqv, 2, 64);
      sqv += __shfl_xor(sqv, 4, 64);
      sqv += __shfl_xor(sqv, 8, 64);
      if (l15 == 0) ssw[wv][k] = sqv;
    }
  }
  __syncthreads();
  if (t < KK)
    ssq_part[((size_t)dc * BB + b) * KK + t] =
        ssw[0][t] + ssw[1][t] + ssw[2][t] + ssw[3][t];
}

// ---------------------------------------------------------------------------
// K3: fused scales + apply. grid (32 k, 64 b) x 256.
// ---------------------------------------------------------------------------
__global__ __launch_bounds__(256) void k_norm(const float* __restrict__ ssq_part,
    float* __restrict__ out) {
  const int t = threadIdx.x;
  const int k = blockIdx.x;
  const int b = blockIdx.y;
  __shared__ float ssk[32];
  if (t < 32) {
    float sk = 0.f;
    #pragma unroll
    for (int dc = 0; dc < 8; ++dc)
      sk += ssq_part[((size_t)dc * BB + b) * KK + t];
    ssk[t] = sk;
  }
  __syncthreads();
  float gss = 0.f, iv_own = 0.f;
  #pragma unroll
  for (int kk = 0; kk < 32; ++kk) {
    float nk = sqrtf(ssk[kk]);
    float iv = 1.f / fmaxf(nk, 1e-12f);
    float nn = nk * iv;
    gss += nn * nn;
    if (kk == k) iv_own = iv;
  }
  float sc = iv_own / fmaxf(sqrtf(gss), 1e-12f);
  float* row = out + (size_t)b * OUTROW + DDIM + (size_t)k * DDIM;
  #pragma unroll
  for (int h = 0; h < 2; ++h) {
    float4* p = (float4*)(row + h * 1024 + t * 4);
    float4 v = *p;
    v.x *= sc; v.y *= sc; v.z *= sc; v.w *= sc;
    *p = v;
  }
}

// ---------------------------------------------------------------------------
extern "C" void kernel_launch(void* const* d_in, const int* in_sizes, int n_in,
                              void* d_out, int out_size, void* d_ws, size_t ws_size,
                              hipStream_t stream) {
  const float* x       = (const float*)d_in[0];
  const int*   lengths = (const int*)d_in[1];
  const float* W       = (const float*)d_in[2];
  const float* C       = (const float*)d_in[3];
  float* out = (float*)d_out;

  short* Wb     = (short*)d_ws;                          // 32*2048 shorts
  short* aT     = Wb + (size_t)KK * DDIM;                // 64*32*128 shorts
  float* asum_p = (float*)(aT + (size_t)BB * KK * MM);   // 512*32 floats
  float* ssqp   = asum_p + (size_t)512 * KK;             // 8*64*32 floats

  k_prep  <<<dim3(32),     256, 0, stream>>>(W, Wb);
  k_logits<<<dim3(512),    256, 0, stream>>>(x, lengths, Wb, aT, asum_p);
  k_vlad  <<<dim3(8, BB),  256, 0, stream>>>(x, lengths, C, aT, asum_p, out, ssqp);
  k_norm  <<<dim3(KK, BB), 256, 0, stream>>>(ssqp, out);
}

// Round 6
// 143.067 us; speedup vs baseline: 2.8159x; 1.0182x over previous
//
#include <hip/hip_runtime.h>
#include <math.h>

#define BB 64
#define MM 128
#define DDIM 2048
#define KK 32
#define NDC 16                   // d-chunks for k_vlad (128-wide each)
#define OUTROW (DDIM + KK*DDIM)  // 67584

typedef __attribute__((ext_vector_type(8))) short bf16x8;
typedef __attribute__((ext_vector_type(4))) float f32x4;

// float -> bf16 RNE (inputs finite; no NaN handling needed)
__device__ __forceinline__ short f2bf(float f) {
  unsigned u = __builtin_bit_cast(unsigned, f);
  u += 0x7fffu + ((u >> 16) & 1u);
  return (short)(u >> 16);
}
__device__ __forceinline__ unsigned pack2(float lo, float hi) {
  return (unsigned)(unsigned short)f2bf(lo) | ((unsigned)(unsigned short)f2bf(hi) << 16);
}

// ---------------------------------------------------------------------------
// K0: W fp32 -> bf16 once. 65536 elems, 32 blocks x 256 x 8.
// ---------------------------------------------------------------------------
__global__ __launch_bounds__(256) void k_prep(const float* __restrict__ W,
                                              short* __restrict__ Wb) {
  int i = (blockIdx.x * 256 + threadIdx.x) * 8;
  float4 a = *(const float4*)(W + i);
  float4 b = *(const float4*)(W + i + 4);
  bf16x8 o = {f2bf(a.x), f2bf(a.y), f2bf(a.z), f2bf(a.w),
              f2bf(b.x), f2bf(b.y), f2bf(b.z), f2bf(b.w)};
  *(bf16x8*)(Wb + i) = o;
}

// ---------------------------------------------------------------------------
// K1: fused logits GEMM (bf16 MFMA) + ssq + softmax + mask. Unchanged from
// r5 (next round's target if this round's k_vlad split pays off).
// ---------------------------------------------------------------------------
__global__ __launch_bounds__(256, 2) void k_logits(const float* __restrict__ x,
    const int* __restrict__ lengths, const short* __restrict__ Wb,
    short* __restrict__ aT, float* __restrict__ asum_p) {
  const int t = threadIdx.x, wv = t >> 6, lane = t & 63;
  const int l15 = lane & 15, quad = lane >> 4;
  const int fg = blockIdx.x;           // 0..511
  const int g0 = fg * 16;              // first frame of block
  const int b  = fg >> 3;              // 8 blocks per batch
  const int m0 = (fg & 7) * 16;        // frame offset within batch
  const int len = lengths[b];

  if (m0 >= len) {
    // fully-invalid frame group: a == 0 -> write zeros directly, exit.
    if (t < KK) asum_p[(size_t)fg * KK + t] = 0.f;
    const int zk = t >> 3, zoff = (t & 7) * 2;   // 32 k x 16 m = 1024B
    *(unsigned*)(aT + (size_t)b * KK * MM + (size_t)zk * MM + m0 + zoff) = 0u;
    return;
  }

  const bool av = (m0 + l15) < len;    // lane's frame valid (const over loop)
  const float* xrow = x + (size_t)(g0 + l15) * DDIM + wv * 512 + quad * 8;
  const short* w0   = Wb + l15 * DDIM + wv * 512 + quad * 8;
  const short* w1   = w0 + 16 * DDIM;

  f32x4 c0 = {0.f, 0.f, 0.f, 0.f}, c1 = {0.f, 0.f, 0.f, 0.f};
  float ssq = 0.f;
  #pragma unroll
  for (int h = 0; h < 2; ++h) {
    float4 xa[8], xc[8];
    bf16x8 B0[8], B1[8];
    #pragma unroll
    for (int s = 0; s < 8; ++s) {
      const int so = h * 8 + s;
      if (av) {
        xa[s] = *(const float4*)(xrow + so * 32);
        xc[s] = *(const float4*)(xrow + so * 32 + 4);
      } else {
        xa[s] = make_float4(0.f, 0.f, 0.f, 0.f);
        xc[s] = make_float4(0.f, 0.f, 0.f, 0.f);
      }
      B0[s] = *(const bf16x8*)(w0 + so * 32);
      B1[s] = *(const bf16x8*)(w1 + so * 32);
    }
    #pragma unroll
    for (int s = 0; s < 8; ++s) {
      ssq = fmaf(xa[s].x, xa[s].x, ssq); ssq = fmaf(xa[s].y, xa[s].y, ssq);
      ssq = fmaf(xa[s].z, xa[s].z, ssq); ssq = fmaf(xa[s].w, xa[s].w, ssq);
      ssq = fmaf(xc[s].x, xc[s].x, ssq); ssq = fmaf(xc[s].y, xc[s].y, ssq);
      ssq = fmaf(xc[s].z, xc[s].z, ssq); ssq = fmaf(xc[s].w, xc[s].w, ssq);
      bf16x8 A = {f2bf(xa[s].x), f2bf(xa[s].y), f2bf(xa[s].z), f2bf(xa[s].w),
                  f2bf(xc[s].x), f2bf(xc[s].y), f2bf(xc[s].z), f2bf(xc[s].w)};
      c0 = __builtin_amdgcn_mfma_f32_16x16x32_bf16(A, B0[s], c0, 0, 0, 0);
      c1 = __builtin_amdgcn_mfma_f32_16x16x32_bf16(A, B1[s], c1, 0, 0, 0);
    }
  }

  ssq += __shfl_xor(ssq, 16, 64);
  ssq += __shfl_xor(ssq, 32, 64);
  __shared__ float sq[4][16];
  __shared__ float lg[4][16][33];
  if (quad == 0) sq[wv][l15] = ssq;
  // C layout: row(frame) = quad*4+reg, col(k) = l15
  #pragma unroll
  for (int r = 0; r < 4; ++r) {
    lg[wv][quad * 4 + r][l15]      = c0[r];
    lg[wv][quad * 4 + r][16 + l15] = c1[r];
  }
  __syncthreads();

  // 16 threads per frame, 2 clusters each
  const int fr = t >> 4, kk = (t & 15) * 2;
  float s0 = 0.f, s1 = 0.f;
  #pragma unroll
  for (int w = 0; w < 4; ++w) { s0 += lg[w][fr][kk]; s1 += lg[w][fr][kk + 1]; }
  float ss  = sq[0][fr] + sq[1][fr] + sq[2][fr] + sq[3][fr];
  float inv = 1.f / fmaxf(sqrtf(ss), 1e-12f);
  s0 *= inv; s1 *= inv;
  float mx = fmaxf(s0, s1);
  mx = fmaxf(mx, __shfl_xor(mx, 1, 64));
  mx = fmaxf(mx, __shfl_xor(mx, 2, 64));
  mx = fmaxf(mx, __shfl_xor(mx, 4, 64));
  mx = fmaxf(mx, __shfl_xor(mx, 8, 64));
  float e0 = __expf(s0 - mx), e1 = __expf(s1 - mx);
  float se = e0 + e1;
  se += __shfl_xor(se, 1, 64);
  se += __shfl_xor(se, 2, 64);
  se += __shfl_xor(se, 4, 64);
  se += __shfl_xor(se, 8, 64);
  const bool valid = (m0 + fr) < len;
  float rr = valid ? (1.f / se) : 0.f;
  float a0 = e0 * rr, a1 = e1 * rr;

  __syncthreads();                    // done reading lg; reuse for asum
  lg[0][fr][kk] = a0; lg[0][fr][kk + 1] = a1;
  __syncthreads();
  if (t < KK) {
    float s = 0.f;
    #pragma unroll
    for (int f = 0; f < 16; ++f) s += lg[0][f][t];
    asum_p[(size_t)fg * KK + t] = s;
  }
  // a' = a * invn, transposed store [b][k][m]
  short* ap = aT + (size_t)b * KK * MM + m0 + fr;
  ap[(size_t)kk * MM]       = f2bf(a0 * inv);
  ap[(size_t)(kk + 1) * MM] = f2bf(a1 * inv);
}

// ---------------------------------------------------------------------------
// K2: vlad GEMM, FINE-SPLIT for TLP: grid (16 dc, 64 b) = 1024 blocks
// (4/CU vs the old grid-limited 2/CU). d-chunk = 128; the 4 waves tile
// (m-half mh x d-half dh): each wave = 64 d x 64 m partial with the SAME
// per-wave load/LDS/MFMA geometry as before, half the m-range (ms 0..1).
// m-partials are combined by a lane-aligned LDS exchange (wave pair splits
// k: mh=0 keeps k0-15, mh=1 keeps k16-31) reusing xbt via a union (both
// 20480B). launch_bounds(256,4) pins VGPR<=128 -> 4 blocks/CU guaranteed.
// ---------------------------------------------------------------------------
__global__ __launch_bounds__(256, 4) void k_vlad(const float* __restrict__ x,
    const int* __restrict__ lengths, const float* __restrict__ Cc,
    const short* __restrict__ aT, const float* __restrict__ asum_p,
    float* __restrict__ out, float* __restrict__ ssq_part) {
  const int t = threadIdx.x, wv = t >> 6, lane = t & 63;
  const int l15 = lane & 15, quad = lane >> 4;
  const int dc = blockIdx.x, b = blockIdx.y;
  const int dh = wv & 1, mh = wv >> 1;
  const int dwb = dc * 128 + dh * 64;   // wave d-base (64 wide)
  const int mb  = mh * 64;              // wave m-base (64 frames)
  const int len = lengths[b];

  __shared__ __attribute__((aligned(16))) char ubuf[20480];
  short (*xbt)[64][40]     = (short(*)[64][40])ubuf;      // [wv][d-loc][m-slot]
  float (*exch)[2][64][20] = (float(*)[2][64][20])ubuf;   // [dh][writer mh][lane][16+pad]
  __shared__ float  asl[KK];
  __shared__ float4 avp[2][16];         // [dh][l15] avg partial of mh=1
  __shared__ float  ssw[4][17];         // [wv][k-local]

  if (t < KK) {
    float s = 0.f;
    #pragma unroll
    for (int p = 0; p < 8; ++p) s += asum_p[(size_t)(b * 8 + p) * KK + t];
    asl[t] = s;
  }

  const float* xb  = x  + (size_t)b * MM * DDIM;
  const short* at0 = aT + (size_t)b * KK * MM + l15 * MM + mb + quad * 8;

  const int q4   = l15 * 4;             // lane's 4 staged d-rows
  const int mrow = quad * 2;            // even m within pass group
  const int keyw = l15 & 3;             // store swizzle key
  const int keyr = (l15 >> 2) & 3;      // read swizzle key

  // ---- preload A-frags (L2-hot) ----
  bf16x8 A0[2], A1[2];
  #pragma unroll
  for (int ms = 0; ms < 2; ++ms) {
    A0[ms] = *(const bf16x8*)(at0 + ms * 32);
    A1[ms] = *(const bf16x8*)(at0 + 16 * MM + ms * 32);
  }

  // ---- preload all x (16 independent float4 loads in flight, masked) ----
  float4 v0[8], v1[8];
  #pragma unroll
  for (int ms = 0; ms < 2; ++ms) {
    #pragma unroll
    for (int p = 0; p < 4; ++p) {
      const int m = mb + ms * 32 + p * 8 + mrow;
      const float* xr = xb + (size_t)m * DDIM + dwb + q4;
      v0[ms * 4 + p] = (m < len) ? *(const float4*)xr
                                 : make_float4(0.f, 0.f, 0.f, 0.f);
      v1[ms * 4 + p] = (m + 1 < len) ? *(const float4*)(xr + DDIM)
                                     : make_float4(0.f, 0.f, 0.f, 0.f);
    }
  }

  // avgpool partial over this wave's m-half (zero-fill makes masking free)
  float avg[4] = {0.f, 0.f, 0.f, 0.f};
  #pragma unroll
  for (int i = 0; i < 8; ++i) {
    avg[0] += v0[i].x + v1[i].x;
    avg[1] += v0[i].y + v1[i].y;
    avg[2] += v0[i].z + v1[i].z;
    avg[3] += v0[i].w + v1[i].w;
  }
  #pragma unroll
  for (int c = 0; c < 4; ++c) {
    avg[c] += __shfl_xor(avg[c], 16, 64);
    avg[c] += __shfl_xor(avg[c], 32, 64);
  }
  if (mh == 1 && quad == 0)
    avp[dh][l15] = make_float4(avg[0], avg[1], avg[2], avg[3]);

  f32x4 acc0[4], acc1[4];
  #pragma unroll
  for (int nt = 0; nt < 4; ++nt) {
    acc0[nt] = (f32x4){0.f, 0.f, 0.f, 0.f};
    acc1[nt] = (f32x4){0.f, 0.f, 0.f, 0.f};
  }

  #pragma unroll
  for (int ms = 0; ms < 2; ++ms) {
    #pragma unroll
    for (int p = 0; p < 4; ++p) {
      const int i = ms * 4 + p;
      const int mls = (p ^ keyw) * 8 + mrow;  // swizzled m-slot
      *(unsigned*)&xbt[wv][q4 + 0][mls] = pack2(v0[i].x, v1[i].x);
      *(unsigned*)&xbt[wv][q4 + 1][mls] = pack2(v0[i].y, v1[i].y);
      *(unsigned*)&xbt[wv][q4 + 2][mls] = pack2(v0[i].z, v1[i].z);
      *(unsigned*)&xbt[wv][q4 + 3][mls] = pack2(v0[i].w, v1[i].w);
    }
    // wave-private tile: same-wave DS ordering is program order
    #pragma unroll
    for (int nt = 0; nt < 4; ++nt) {
      bf16x8 B = *(const bf16x8*)&xbt[wv][nt * 16 + l15][(quad ^ keyr) * 8];
      acc0[nt] = __builtin_amdgcn_mfma_f32_16x16x32_bf16(A0[ms], B, acc0[nt], 0, 0, 0);
      acc1[nt] = __builtin_amdgcn_mfma_f32_16x16x32_bf16(A1[ms], B, acc1[nt], 0, 0, 0);
    }
  }

  // wave-uniform k-split: keep kt==mh, donate the other half
  f32x4 keep[4], give[4];
  if (mh == 0) {
    #pragma unroll
    for (int nt = 0; nt < 4; ++nt) { keep[nt] = acc0[nt]; give[nt] = acc1[nt]; }
  } else {
    #pragma unroll
    for (int nt = 0; nt < 4; ++nt) { keep[nt] = acc1[nt]; give[nt] = acc0[nt]; }
  }

  __syncthreads();   // all xbt reads done (union safe); avp, asl visible
  #pragma unroll
  for (int nt = 0; nt < 4; ++nt)
    *(f32x4*)&exch[dh][mh][lane][nt * 4] = give[nt];

  // avgpool finish (mh=0 waves own the write)
  if (mh == 0 && quad == 0) {
    float4 pa = avp[dh][l15];
    float rl = 1.f / (float)len;
    *(float4*)(out + (size_t)b * OUTROW + dwb + q4) =
        make_float4((avg[0] + pa.x) * rl, (avg[1] + pa.y) * rl,
                    (avg[2] + pa.z) * rl, (avg[3] + pa.w) * rl);
  }

  __syncthreads();   // exch stores visible
  #pragma unroll
  for (int nt = 0; nt < 4; ++nt)
    keep[nt] += *(const f32x4*)&exch[dh][1 - mh][lane][nt * 4];

  // residual + ssq for this wave's 16 k x 64 d
  float* orow = out + (size_t)b * OUTROW + DDIM;
  #pragma unroll
  for (int r = 0; r < 4; ++r) {
    const int k = mh * 16 + quad * 4 + r;
    const float as = asl[k];
    float sqv = 0.f;
    #pragma unroll
    for (int nt = 0; nt < 4; ++nt) {
      const int d = dwb + nt * 16 + l15;
      float v = keep[nt][r] - as * Cc[(size_t)k * DDIM + d];
      orow[(size_t)k * DDIM + d] = v;
      sqv = fmaf(v, v, sqv);
    }
    sqv += __shfl_xor(sqv, 1, 64);
    sqv += __shfl_xor(sqv, 2, 64);
    sqv += __shfl_xor(sqv, 4, 64);
    sqv += __shfl_xor(sqv, 8, 64);
    if (l15 == 0) ssw[wv][quad * 4 + r] = sqv;
  }
  __syncthreads();
  if (t < KK) {
    const int mt = t >> 4, kl = t & 15;   // waves mt*2 and mt*2+1 hold k=t
    ssq_part[((size_t)dc * BB + b) * KK + t] = ssw[mt * 2][kl] + ssw[mt * 2 + 1][kl];
  }
}

// ---------------------------------------------------------------------------
// K3: fused scales + apply. grid (32 k, 64 b) x 256. NDC=16 partials now.
// ---------------------------------------------------------------------------
__global__ __launch_bounds__(256) void k_norm(const float* __restrict__ ssq_part,
    float* __restrict__ out) {
  const int t = threadIdx.x;
  const int k = blockIdx.x;
  const int b = blockIdx.y;
  __shared__ float ssk[32];
  if (t < 32) {
    float sk = 0.f;
    #pragma unroll
    for (int dc = 0; dc < NDC; ++dc)
      sk += ssq_part[((size_t)dc * BB + b) * KK + t];
    ssk[t] = sk;
  }
  __syncthreads();
  float gss = 0.f, iv_own = 0.f;
  #pragma unroll
  for (int kk = 0; kk < 32; ++kk) {
    float nk = sqrtf(ssk[kk]);
    float iv = 1.f / fmaxf(nk, 1e-12f);
    float nn = nk * iv;
    gss += nn * nn;
    if (kk == k) iv_own = iv;
  }
  float sc = iv_own / fmaxf(sqrtf(gss), 1e-12f);
  float* row = out + (size_t)b * OUTROW + DDIM + (size_t)k * DDIM;
  #pragma unroll
  for (int h = 0; h < 2; ++h) {
    float4* p = (float4*)(row + h * 1024 + t * 4);
    float4 v = *p;
    v.x *= sc; v.y *= sc; v.z *= sc; v.w *= sc;
    *p = v;
  }
}

// ---------------------------------------------------------------------------
extern "C" void kernel_launch(void* const* d_in, const int* in_sizes, int n_in,
                              void* d_out, int out_size, void* d_ws, size_t ws_size,
                              hipStream_t stream) {
  const float* x       = (const float*)d_in[0];
  const int*   lengths = (const int*)d_in[1];
  const float* W       = (const float*)d_in[2];
  const float* C       = (const float*)d_in[3];
  float* out = (float*)d_out;

  short* Wb     = (short*)d_ws;                          // 32*2048 shorts
  short* aT     = Wb + (size_t)KK * DDIM;                // 64*32*128 shorts
  float* asum_p = (float*)(aT + (size_t)BB * KK * MM);   // 512*32 floats
  float* ssqp   = asum_p + (size_t)512 * KK;             // 16*64*32 floats

  k_prep  <<<dim3(32),      256, 0, stream>>>(W, Wb);
  k_logits<<<dim3(512),     256, 0, stream>>>(x, lengths, Wb, aT, asum_p);
  k_vlad  <<<dim3(NDC, BB), 256, 0, stream>>>(x, lengths, C, aT, asum_p, out, ssqp);
  k_norm  <<<dim3(KK, BB),  256, 0, stream>>>(ssqp, out);
}